// Round 9
// baseline (337.787 us; speedup 1.0000x reference)
//
#include <hip/hip_runtime.h>

#define TOK     50176
#define NQKV    1152
#define DMODEL  384
#define HW      3136
#define NWIN    1024

typedef __bf16 bf16x8 __attribute__((ext_vector_type(8)));
typedef float  f32x4  __attribute__((ext_vector_type(4)));

__device__ __forceinline__ __bf16 f2bf(float f) {            // round-to-nearest-even
  unsigned u = __float_as_uint(f);
  u += 0x7fffu + ((u >> 16) & 1u);
  unsigned short s = (unsigned short)(u >> 16);
  return __builtin_bit_cast(__bf16, s);
}
__device__ __forceinline__ unsigned short f2bfu(float f) {
  return __builtin_bit_cast(unsigned short, f2bf(f));
}
__device__ __forceinline__ float bf2f(__bf16 b) {
  return __uint_as_float(((unsigned)__builtin_bit_cast(unsigned short, b)) << 16);
}

// ---------------------------------------------------------------------------
// Gather x (16,384,56,56) fp32 -> Xw (50176, 384) bf16 token-major.
// ---------------------------------------------------------------------------
__global__ __launch_bounds__(256) void gather_x(const float* __restrict__ x,
                                                __bf16* __restrict__ Xw) {
  __shared__ __bf16 lt[392 * 48];
  const int ct = blockIdx.x, hr = blockIdx.y, b = blockIdx.z;
  const int tid = threadIdx.x;
  const float* xb = x + ((size_t)(b * 384 + ct * 48)) * HW + hr * 7 * 56;

  for (int u = tid; u < 48 * 7 * 14; u += 256) {
    const int ch = u / 98, rem = u % 98;
    const int h7 = rem / 14, w4 = rem % 14;
    const float4 v = *(const float4*)&xb[(size_t)ch * HW + h7 * 56 + 4 * w4];
    const float vv[4] = {v.x, v.y, v.z, v.w};
#pragma unroll
    for (int e = 0; e < 4; ++e) {
      const int w = 4 * w4 + e;
      const int t = (w / 7) * 49 + h7 * 7 + (w % 7);
      lt[t * 48 + ch] = f2bf(vv[e]);
    }
  }
  __syncthreads();

  const size_t tokbase = (size_t)(b * 64 + hr * 8) * 49;
  for (int u = tid; u < 392 * 6; u += 256) {
    const int t = u / 6, c6 = u % 6;
    const bf16x8 vv = *(const bf16x8*)&lt[t * 48 + 8 * c6];
    *(bf16x8*)&Xw[(tokbase + t) * DMODEL + ct * 48 + 8 * c6] = vv;
  }
}

// ---------------------------------------------------------------------------
// Unscatter: attnP (50176,384) bf16 token-major -> out (16,384,56,56) fp32.
// ---------------------------------------------------------------------------
__global__ __launch_bounds__(256) void unscatter(const __bf16* __restrict__ P,
                                                 float* __restrict__ out) {
  __shared__ __bf16 lt[392 * 48];
  const int ct = blockIdx.x, hr = blockIdx.y, b = blockIdx.z;
  const int tid = threadIdx.x;
  const size_t tokbase = (size_t)(b * 64 + hr * 8) * 49;

  for (int u = tid; u < 392 * 6; u += 256) {
    const int t = u / 6, c6 = u % 6;
    *(bf16x8*)&lt[t * 48 + 8 * c6] =
        *(const bf16x8*)&P[(tokbase + t) * DMODEL + ct * 48 + 8 * c6];
  }
  __syncthreads();

  float* ob = out + ((size_t)(b * 384 + ct * 48)) * HW + hr * 7 * 56;
  for (int u = tid; u < 48 * 98; u += 256) {
    const int ch = u / 98, rem = u % 98;
    const int h7 = rem / 14, w4 = rem % 14;
    float4 o;
    float* oo = (float*)&o;
#pragma unroll
    for (int e = 0; e < 4; ++e) {
      const int w = 4 * w4 + e;
      const int t = (w / 7) * 49 + h7 * 7 + (w % 7);
      oo[e] = bf2f(lt[t * 48 + ch]);
    }
    *(float4*)&ob[(size_t)ch * HW + h7 * 56 + 4 * w4] = o;
  }
}

// Transpose+convert weights: WqkvT (1152,384) bf16, WprojT (384,384) bf16.
__global__ void conv_w(const float* __restrict__ Wqkv, const float* __restrict__ Wproj,
                       __bf16* __restrict__ WqkvT, __bf16* __restrict__ WprojT) {
  const int idx = blockIdx.x * 256 + threadIdx.x;
  if (idx < DMODEL * NQKV) {
    const int k = idx / NQKV, n = idx % NQKV;
    WqkvT[(size_t)n * DMODEL + k] = f2bf(Wqkv[idx]);
  }
  if (idx < DMODEL * DMODEL) {
    const int k = idx / DMODEL, n = idx % DMODEL;
    WprojT[(size_t)n * DMODEL + k] = f2bf(Wproj[idx]);
  }
}

// ---------------------------------------------------------------------------
// FLAT bf16 MFMA GEMM: no LDS, no barriers. 128x128 block, 4 waves (2Mx2N),
// each wave 64x64. A/B fragments loaded global->VGPR directly (16 rows x 64B
// per wave-load, coalesced; A panels L2-hot via XCD swizzle, B L1/L2-hot).
// K=384 fully unrolled -> compiler hoists loads for deep latency hiding;
// each wave self-paces (no inter-wave sync at all).
// Transposed accumulator -> ushort4 packed bf16 stores + bias.
// ---------------------------------------------------------------------------
__global__ __launch_bounds__(256) void gemm_flat(const __bf16* __restrict__ A,
                                                 const __bf16* __restrict__ BT,
                                                 const float* __restrict__ bias,
                                                 __bf16* __restrict__ Cout, int Ncols) {
  const int tid  = threadIdx.x;
  const int lane = tid & 63;
  const int wid  = tid >> 6;

  // bijective XCD-chunked swizzle (m204 variant; works for any nwg)
  const int nwg  = gridDim.x * gridDim.y;
  const int orig = blockIdx.y * gridDim.x + blockIdx.x;
  const int q    = nwg >> 3, r = nwg & 7;
  const int xcd  = orig & 7, pos = orig >> 3;
  const int start = (xcd < r) ? xcd * (q + 1) : r * (q + 1) + (xcd - r) * q;
  const int w    = start + pos;
  const int bn   = (w % gridDim.x) << 7;   // N tile: 128
  const int bm   = (w / gridDim.x) << 7;   // M tile: 128

  const int wm = (wid >> 1) << 6;   // 0,64
  const int wn = (wid & 1) << 6;    // 0,64
  const int lrow = lane & 15;
  const int lk8  = (lane >> 4) << 3;

  const __bf16* pa = A  + (size_t)(bm + wm + lrow) * DMODEL + lk8;
  const __bf16* pb = BT + (size_t)(bn + wn + lrow) * DMODEL + lk8;

  f32x4 acc[4][4] = {};   // acc[j][i]: j = channel frag, i = token frag

#pragma unroll
  for (int kt = 0; kt < 12; ++kt) {
    const int koff = kt << 5;
    bf16x8 av[4], bv[4];
#pragma unroll
    for (int i = 0; i < 4; ++i)
      av[i] = *(const bf16x8*)(pa + (size_t)i * 16 * DMODEL + koff);
#pragma unroll
    for (int j = 0; j < 4; ++j)
      bv[j] = *(const bf16x8*)(pb + (size_t)j * 16 * DMODEL + koff);
#pragma unroll
    for (int i = 0; i < 4; ++i)
#pragma unroll
      for (int j = 0; j < 4; ++j)
        acc[j][i] = __builtin_amdgcn_mfma_f32_16x16x32_bf16(bv[j], av[i], acc[j][i], 0, 0, 0);
  }

  const int lr = lane & 15, g = lane >> 4;
  const int tok0 = bm + wm + lr;
  const int ch0  = bn + wn + (g << 2);

#pragma unroll
  for (int j = 0; j < 4; ++j) {
    const int ch = ch0 + 16 * j;
    const float4 b4 = *(const float4*)&bias[ch];
#pragma unroll
    for (int i = 0; i < 4; ++i) {
      const int token = tok0 + 16 * i;
      ushort4 pk;
      pk.x = f2bfu(acc[j][i][0] + b4.x);
      pk.y = f2bfu(acc[j][i][1] + b4.y);
      pk.z = f2bfu(acc[j][i][2] + b4.z);
      pk.w = f2bfu(acc[j][i][3] + b4.w);
      *(ushort4*)&Cout[(size_t)token * Ncols + ch] = pk;
    }
  }
}

// ---------------------------------------------------------------------------
// MFMA attention: one wave per (window, head). Pad 49 -> 64. (unchanged)
// ---------------------------------------------------------------------------
__global__ __launch_bounds__(64) void attn_mfma(const __bf16* __restrict__ qkv,
                                                __bf16* __restrict__ attnO) {
  __shared__ __align__(16) __bf16 lds[96 * 72];
  __bf16* p_lds = lds;
  __bf16* vt    = lds + 64 * 72;

  const int lane = threadIdx.x;
  const int win  = blockIdx.x;
  const int h    = blockIdx.y;
  const int lr = lane & 15, g = lane >> 4;
  const size_t rowbase = (size_t)win * 49;

  int rr[4];
#pragma unroll
  for (int f = 0; f < 4; ++f) rr[f] = (16 * f + lr > 48) ? 48 : (16 * f + lr);

  const int co = h * 32 + 8 * g;

  bf16x8 av[4], bv[4];
#pragma unroll
  for (int f = 0; f < 4; ++f) {
    const __bf16* rp = qkv + (rowbase + rr[f]) * NQKV + co;
    av[f] = *(const bf16x8*)(rp + 384);
    bv[f] = *(const bf16x8*)(rp);
  }

  ushort4 vreg[7];
#pragma unroll
  for (int u = 0; u < 7; ++u) {
    const int unit = lane + (u << 6);
    if (unit < 392) {
      const int k = unit >> 3, dq = unit & 7;
      vreg[u] = *(const ushort4*)(qkv + (rowbase + k) * NQKV + 768 + h * 32 + 4 * dq);
    }
  }

  f32x4 acc[4][4] = {};
#pragma unroll
  for (int i = 0; i < 4; ++i)
#pragma unroll
    for (int j = 0; j < 4; ++j)
      acc[i][j] = __builtin_amdgcn_mfma_f32_16x16x32_bf16(av[i], bv[j], acc[i][j], 0, 0, 0);

  const float scale = 0.17677669529663687f;
#pragma unroll
  for (int i = 0; i < 4; ++i)
#pragma unroll
    for (int j = 0; j < 4; ++j)
#pragma unroll
      for (int r = 0; r < 4; ++r) {
        float v = acc[i][j][r] * scale;
        if (i == 3 && (4 * g + r) != 0) v = -1e30f;
        acc[i][j][r] = v;
      }

#pragma unroll
  for (int u = 0; u < 7; ++u) {
    const int unit = lane + (u << 6);
    if (unit < 392) {
      const int k = unit >> 3, dq = unit & 7;
      const ushort4 vv = vreg[u];
      vt[(4 * dq + 0) * 72 + k] = __builtin_bit_cast(__bf16, vv.x);
      vt[(4 * dq + 1) * 72 + k] = __builtin_bit_cast(__bf16, vv.y);
      vt[(4 * dq + 2) * 72 + k] = __builtin_bit_cast(__bf16, vv.z);
      vt[(4 * dq + 3) * 72 + k] = __builtin_bit_cast(__bf16, vv.w);
    }
  }

#pragma unroll
  for (int j = 0; j < 4; ++j) {
    float mx = -1e30f;
#pragma unroll
    for (int i = 0; i < 4; ++i)
#pragma unroll
      for (int r = 0; r < 4; ++r) mx = fmaxf(mx, acc[i][j][r]);
    mx = fmaxf(mx, __shfl_xor(mx, 16));
    mx = fmaxf(mx, __shfl_xor(mx, 32));
    float sum = 0.f;
#pragma unroll
    for (int i = 0; i < 4; ++i)
#pragma unroll
      for (int r = 0; r < 4; ++r) {
        const float e = __expf(acc[i][j][r] - mx);
        acc[i][j][r] = e;
        sum += e;
      }
    sum += __shfl_xor(sum, 16);
    sum += __shfl_xor(sum, 32);
    const float inv = 1.f / sum;
#pragma unroll
    for (int i = 0; i < 4; ++i) {
      ushort4 pk;
      pk.x = f2bfu(acc[i][j][0] * inv);
      pk.y = f2bfu(acc[i][j][1] * inv);
      pk.z = f2bfu(acc[i][j][2] * inv);
      pk.w = f2bfu(acc[i][j][3] * inv);
      *(ushort4*)&p_lds[(16 * j + lr) * 72 + 16 * i + 4 * g] = pk;
    }
  }

  f32x4 o[2][4] = {};
#pragma unroll
  for (int ks = 0; ks < 2; ++ks) {
    bf16x8 a2[2], b2[4];
#pragma unroll
    for (int i2 = 0; i2 < 2; ++i2)
      a2[i2] = *(const bf16x8*)&vt[(16 * i2 + lr) * 72 + 32 * ks + 8 * g];
#pragma unroll
    for (int j2 = 0; j2 < 4; ++j2)
      b2[j2] = *(const bf16x8*)&p_lds[(16 * j2 + lr) * 72 + 32 * ks + 8 * g];
#pragma unroll
    for (int i2 = 0; i2 < 2; ++i2)
#pragma unroll
      for (int j2 = 0; j2 < 4; ++j2)
        o[i2][j2] = __builtin_amdgcn_mfma_f32_16x16x32_bf16(a2[i2], b2[j2], o[i2][j2], 0, 0, 0);
  }

#pragma unroll
  for (int j2 = 0; j2 < 4; ++j2) {
    const int q = 16 * j2 + lr;
    if (q <= 48) {
#pragma unroll
      for (int i2 = 0; i2 < 2; ++i2) {
        ushort4 ok;
        ok.x = f2bfu(o[i2][j2][0]);
        ok.y = f2bfu(o[i2][j2][1]);
        ok.z = f2bfu(o[i2][j2][2]);
        ok.w = f2bfu(o[i2][j2][3]);
        *(ushort4*)&attnO[(rowbase + q) * DMODEL + h * 32 + 16 * i2 + 4 * g] = ok;
      }
    }
  }
}

extern "C" void kernel_launch(void* const* d_in, const int* in_sizes, int n_in,
                              void* d_out, int out_size, void* d_ws, size_t ws_size,
                              hipStream_t stream) {
  const float* x     = (const float*)d_in[0];
  const float* Wqkv  = (const float*)d_in[1];
  const float* bqkv  = (const float*)d_in[2];
  const float* Wproj = (const float*)d_in[3];
  const float* bproj = (const float*)d_in[4];
  float* out = (float*)d_out;

  char* ws = (char*)d_ws;
  __bf16* Xw     = (__bf16*)ws;  ws += (size_t)TOK * DMODEL * 2;   // 38.5 MB
  __bf16* qkvb   = (__bf16*)ws;  ws += (size_t)TOK * NQKV * 2;     // 115.6 MB
  __bf16* attnO  = (__bf16*)ws;  ws += (size_t)TOK * DMODEL * 2;   // 38.5 MB
  __bf16* attnP  = (__bf16*)ws;  ws += (size_t)TOK * DMODEL * 2;   // 38.5 MB
  __bf16* WqkvT  = (__bf16*)ws;  ws += (size_t)NQKV * DMODEL * 2;
  __bf16* WprojT = (__bf16*)ws;

  gather_x<<<dim3(8, 8, 16), 256, 0, stream>>>(x, Xw);
  conv_w<<<1728, 256, 0, stream>>>(Wqkv, Wproj, WqkvT, WprojT);
  gemm_flat<<<dim3(NQKV / 128, TOK / 128), 256, 0, stream>>>(Xw, WqkvT, bqkv, qkvb, NQKV);
  attn_mfma<<<dim3(NWIN, 12), 64, 0, stream>>>(qkvb, attnO);
  gemm_flat<<<dim3(DMODEL / 128, TOK / 128), 256, 0, stream>>>(attnO, WprojT, bproj, attnP, DMODEL);
  unscatter<<<dim3(8, 8, 16), 256, 0, stream>>>(attnP, out);
}

// Round 10
// 225.047 us; speedup vs baseline: 1.5010x; 1.5010x over previous
//
#include <hip/hip_runtime.h>

#define TOK     50176
#define NQKV    1152
#define DMODEL  384
#define HW      3136
#define NWIN    1024

typedef __bf16 bf16x8 __attribute__((ext_vector_type(8)));
typedef float  f32x4  __attribute__((ext_vector_type(4)));

__device__ __forceinline__ __bf16 f2bf(float f) {            // round-to-nearest-even
  unsigned u = __float_as_uint(f);
  u += 0x7fffu + ((u >> 16) & 1u);
  unsigned short s = (unsigned short)(u >> 16);
  return __builtin_bit_cast(__bf16, s);
}
__device__ __forceinline__ unsigned short f2bfu(float f) {
  return __builtin_bit_cast(unsigned short, f2bf(f));
}
__device__ __forceinline__ float bf2f(__bf16 b) {
  return __uint_as_float(((unsigned)__builtin_bit_cast(unsigned short, b)) << 16);
}
__device__ __forceinline__ void gload_lds16(const void* g, void* l) {
  __builtin_amdgcn_global_load_lds(
      (const __attribute__((address_space(1))) unsigned int*)g,
      (__attribute__((address_space(3))) unsigned int*)l, 16, 0, 0);
}

// ---------------------------------------------------------------------------
// Gather x (16,384,56,56) fp32 -> Xw (50176, 384) bf16 token-major.
// ---------------------------------------------------------------------------
__global__ __launch_bounds__(256) void gather_x(const float* __restrict__ x,
                                                __bf16* __restrict__ Xw) {
  __shared__ __bf16 lt[392 * 48];
  const int ct = blockIdx.x, hr = blockIdx.y, b = blockIdx.z;
  const int tid = threadIdx.x;
  const float* xb = x + ((size_t)(b * 384 + ct * 48)) * HW + hr * 7 * 56;

  for (int u = tid; u < 48 * 7 * 14; u += 256) {
    const int ch = u / 98, rem = u % 98;
    const int h7 = rem / 14, w4 = rem % 14;
    const float4 v = *(const float4*)&xb[(size_t)ch * HW + h7 * 56 + 4 * w4];
    const float vv[4] = {v.x, v.y, v.z, v.w};
#pragma unroll
    for (int e = 0; e < 4; ++e) {
      const int w = 4 * w4 + e;
      const int t = (w / 7) * 49 + h7 * 7 + (w % 7);
      lt[t * 48 + ch] = f2bf(vv[e]);
    }
  }
  __syncthreads();

  const size_t tokbase = (size_t)(b * 64 + hr * 8) * 49;
  for (int u = tid; u < 392 * 6; u += 256) {
    const int t = u / 6, c6 = u % 6;
    const bf16x8 vv = *(const bf16x8*)&lt[t * 48 + 8 * c6];
    *(bf16x8*)&Xw[(tokbase + t) * DMODEL + ct * 48 + 8 * c6] = vv;
  }
}

// ---------------------------------------------------------------------------
// Unscatter: attnP (50176,384) bf16 token-major -> out (16,384,56,56) fp32.
// ---------------------------------------------------------------------------
__global__ __launch_bounds__(256) void unscatter(const __bf16* __restrict__ P,
                                                 float* __restrict__ out) {
  __shared__ __bf16 lt[392 * 48];
  const int ct = blockIdx.x, hr = blockIdx.y, b = blockIdx.z;
  const int tid = threadIdx.x;
  const size_t tokbase = (size_t)(b * 64 + hr * 8) * 49;

  for (int u = tid; u < 392 * 6; u += 256) {
    const int t = u / 6, c6 = u % 6;
    *(bf16x8*)&lt[t * 48 + 8 * c6] =
        *(const bf16x8*)&P[(tokbase + t) * DMODEL + ct * 48 + 8 * c6];
  }
  __syncthreads();

  float* ob = out + ((size_t)(b * 384 + ct * 48)) * HW + hr * 7 * 56;
  for (int u = tid; u < 48 * 98; u += 256) {
    const int ch = u / 98, rem = u % 98;
    const int h7 = rem / 14, w4 = rem % 14;
    float4 o;
    float* oo = (float*)&o;
#pragma unroll
    for (int e = 0; e < 4; ++e) {
      const int w = 4 * w4 + e;
      const int t = (w / 7) * 49 + h7 * 7 + (w % 7);
      oo[e] = bf2f(lt[t * 48 + ch]);
    }
    *(float4*)&ob[(size_t)ch * HW + h7 * 56 + 4 * w4] = o;
  }
}

// Transpose+convert weights: WqkvT (1152,384) bf16, WprojT (384,384) bf16.
__global__ void conv_w(const float* __restrict__ Wqkv, const float* __restrict__ Wproj,
                       __bf16* __restrict__ WqkvT, __bf16* __restrict__ WprojT) {
  const int idx = blockIdx.x * 256 + threadIdx.x;
  if (idx < DMODEL * NQKV) {
    const int k = idx / NQKV, n = idx % NQKV;
    WqkvT[(size_t)n * DMODEL + k] = f2bf(Wqkv[idx]);
  }
  if (idx < DMODEL * DMODEL) {
    const int k = idx / DMODEL, n = idx % DMODEL;
    WprojT[(size_t)n * DMODEL + k] = f2bf(Wproj[idx]);
  }
}

// ---------------------------------------------------------------------------
// bf16 MFMA GEMM, 256x128 tile, BK=32, 256 threads = 4 waves, per-wave
// 128x64 output (wm in {0,128}, wn in {0,64}) -- 12 ds_read_b128 feed
// 32 MFMAs per wave per K-step (2.67 MFMA/read vs 2.0 of the 64x64
// blocking; block LDS traffic 88KB -> 72KB per K-step). Double-buffered
// LDS via global_load_lds, 2-phase __syncthreads loop (proven r6
// structure). __launch_bounds__(256,2): acc128+operands ~200 VGPR,
// 2 waves/SIMD, 2 blocks/CU. Bijective XCD-chunk swizzle.
// Transposed accumulator -> ushort4 packed bf16 stores + bias.
// ---------------------------------------------------------------------------
__global__ __launch_bounds__(256, 2) void gemm256(const __bf16* __restrict__ A,
                                                  const __bf16* __restrict__ BT,
                                                  const float* __restrict__ bias,
                                                  __bf16* __restrict__ Cout, int Ncols) {
  __shared__ __align__(16) __bf16 As[2][256 * 32];
  __shared__ __align__(16) __bf16 Bs[2][128 * 32];
  const int tid  = threadIdx.x;
  const int lane = tid & 63;
  const int wid  = tid >> 6;

  // bijective XCD-chunked swizzle (m204 variant; works for any nwg)
  const int nwg  = gridDim.x * gridDim.y;
  const int orig = blockIdx.y * gridDim.x + blockIdx.x;
  const int q    = nwg >> 3, r = nwg & 7;
  const int xcd  = orig & 7, pos = orig >> 3;
  const int start = (xcd < r) ? xcd * (q + 1) : r * (q + 1) + (xcd - r) * q;
  const int w    = start + pos;
  const int bn   = (w % gridDim.x) << 7;   // N tile: 128
  const int bm   = (w / gridDim.x) << 8;   // M tile: 256

  // staging sources: each wave's gload covers 16 rows x 64B; 4 A-instr + 2 B-instr
  const __bf16* a0 = A  + (size_t)(bm +       (tid >> 2)) * DMODEL + ((tid & 3) << 3);
  const __bf16* a1 = A  + (size_t)(bm +  64 + (tid >> 2)) * DMODEL + ((tid & 3) << 3);
  const __bf16* a2 = A  + (size_t)(bm + 128 + (tid >> 2)) * DMODEL + ((tid & 3) << 3);
  const __bf16* a3 = A  + (size_t)(bm + 192 + (tid >> 2)) * DMODEL + ((tid & 3) << 3);
  const __bf16* b0 = BT + (size_t)(bn +       (tid >> 2)) * DMODEL + ((tid & 3) << 3);
  const __bf16* b1 = BT + (size_t)(bn +  64 + (tid >> 2)) * DMODEL + ((tid & 3) << 3);

  const int wm = (wid >> 1) << 7;   // 0,128
  const int wn = (wid & 1) << 6;    // 0,64
  const int lrow = lane & 15;
  const int lk8  = (lane >> 4) << 3;

  f32x4 acc[4][8] = {};   // acc[j][i]: j = channel frag (4), i = token frag (8)

  auto stage = [&](int buf, int kt) {
    const int koff = kt << 5;
    gload_lds16(a0 + koff, &As[buf][(wid << 9)]);
    gload_lds16(a1 + koff, &As[buf][2048 + (wid << 9)]);
    gload_lds16(a2 + koff, &As[buf][4096 + (wid << 9)]);
    gload_lds16(a3 + koff, &As[buf][6144 + (wid << 9)]);
    gload_lds16(b0 + koff, &Bs[buf][(wid << 9)]);
    gload_lds16(b1 + koff, &Bs[buf][2048 + (wid << 9)]);
  };

  stage(0, 0);
#pragma unroll 1
  for (int kt = 0; kt < 12; ++kt) {
    __syncthreads();                       // drains vmcnt -> buf[kt&1] ready
    if (kt + 1 < 12) stage((kt + 1) & 1, kt + 1);
    const __bf16* pA = &As[kt & 1][(wm + lrow) * 32 + lk8];
    const __bf16* pB = &Bs[kt & 1][(wn + lrow) * 32 + lk8];
    bf16x8 av[8], bv[4];
#pragma unroll
    for (int i = 0; i < 8; ++i) av[i] = *(const bf16x8*)(pA + i * 16 * 32);
#pragma unroll
    for (int j = 0; j < 4; ++j) bv[j] = *(const bf16x8*)(pB + j * 16 * 32);
#pragma unroll
    for (int i = 0; i < 8; ++i)
#pragma unroll
      for (int j = 0; j < 4; ++j)
        acc[j][i] = __builtin_amdgcn_mfma_f32_16x16x32_bf16(bv[j], av[i], acc[j][i], 0, 0, 0);
  }

  const int lr = lane & 15, g = lane >> 4;
  const int tok0 = bm + wm + lr;
  const int ch0  = bn + wn + (g << 2);

#pragma unroll
  for (int j = 0; j < 4; ++j) {
    const int ch = ch0 + 16 * j;
    const float4 b4 = *(const float4*)&bias[ch];
#pragma unroll
    for (int i = 0; i < 8; ++i) {
      const int token = tok0 + 16 * i;
      ushort4 pk;
      pk.x = f2bfu(acc[j][i][0] + b4.x);
      pk.y = f2bfu(acc[j][i][1] + b4.y);
      pk.z = f2bfu(acc[j][i][2] + b4.z);
      pk.w = f2bfu(acc[j][i][3] + b4.w);
      *(ushort4*)&Cout[(size_t)token * Ncols + ch] = pk;
    }
  }
}

// ---------------------------------------------------------------------------
// MFMA attention: one wave per (window, head). Pad 49 -> 64. (unchanged)
// ---------------------------------------------------------------------------
__global__ __launch_bounds__(64) void attn_mfma(const __bf16* __restrict__ qkv,
                                                __bf16* __restrict__ attnO) {
  __shared__ __align__(16) __bf16 lds[96 * 72];
  __bf16* p_lds = lds;
  __bf16* vt    = lds + 64 * 72;

  const int lane = threadIdx.x;
  const int win  = blockIdx.x;
  const int h    = blockIdx.y;
  const int lr = lane & 15, g = lane >> 4;
  const size_t rowbase = (size_t)win * 49;

  int rr[4];
#pragma unroll
  for (int f = 0; f < 4; ++f) rr[f] = (16 * f + lr > 48) ? 48 : (16 * f + lr);

  const int co = h * 32 + 8 * g;

  bf16x8 av[4], bv[4];
#pragma unroll
  for (int f = 0; f < 4; ++f) {
    const __bf16* rp = qkv + (rowbase + rr[f]) * NQKV + co;
    av[f] = *(const bf16x8*)(rp + 384);
    bv[f] = *(const bf16x8*)(rp);
  }

  ushort4 vreg[7];
#pragma unroll
  for (int u = 0; u < 7; ++u) {
    const int unit = lane + (u << 6);
    if (unit < 392) {
      const int k = unit >> 3, dq = unit & 7;
      vreg[u] = *(const ushort4*)(qkv + (rowbase + k) * NQKV + 768 + h * 32 + 4 * dq);
    }
  }

  f32x4 acc[4][4] = {};
#pragma unroll
  for (int i = 0; i < 4; ++i)
#pragma unroll
    for (int j = 0; j < 4; ++j)
      acc[i][j] = __builtin_amdgcn_mfma_f32_16x16x32_bf16(av[i], bv[j], acc[i][j], 0, 0, 0);

  const float scale = 0.17677669529663687f;
#pragma unroll
  for (int i = 0; i < 4; ++i)
#pragma unroll
    for (int j = 0; j < 4; ++j)
#pragma unroll
      for (int r = 0; r < 4; ++r) {
        float v = acc[i][j][r] * scale;
        if (i == 3 && (4 * g + r) != 0) v = -1e30f;
        acc[i][j][r] = v;
      }

#pragma unroll
  for (int u = 0; u < 7; ++u) {
    const int unit = lane + (u << 6);
    if (unit < 392) {
      const int k = unit >> 3, dq = unit & 7;
      const ushort4 vv = vreg[u];
      vt[(4 * dq + 0) * 72 + k] = __builtin_bit_cast(__bf16, vv.x);
      vt[(4 * dq + 1) * 72 + k] = __builtin_bit_cast(__bf16, vv.y);
      vt[(4 * dq + 2) * 72 + k] = __builtin_bit_cast(__bf16, vv.z);
      vt[(4 * dq + 3) * 72 + k] = __builtin_bit_cast(__bf16, vv.w);
    }
  }

#pragma unroll
  for (int j = 0; j < 4; ++j) {
    float mx = -1e30f;
#pragma unroll
    for (int i = 0; i < 4; ++i)
#pragma unroll
      for (int r = 0; r < 4; ++r) mx = fmaxf(mx, acc[i][j][r]);
    mx = fmaxf(mx, __shfl_xor(mx, 16));
    mx = fmaxf(mx, __shfl_xor(mx, 32));
    float sum = 0.f;
#pragma unroll
    for (int i = 0; i < 4; ++i)
#pragma unroll
      for (int r = 0; r < 4; ++r) {
        const float e = __expf(acc[i][j][r] - mx);
        acc[i][j][r] = e;
        sum += e;
      }
    sum += __shfl_xor(sum, 16);
    sum += __shfl_xor(sum, 32);
    const float inv = 1.f / sum;
#pragma unroll
    for (int i = 0; i < 4; ++i) {
      ushort4 pk;
      pk.x = f2bfu(acc[i][j][0] * inv);
      pk.y = f2bfu(acc[i][j][1] * inv);
      pk.z = f2bfu(acc[i][j][2] * inv);
      pk.w = f2bfu(acc[i][j][3] * inv);
      *(ushort4*)&p_lds[(16 * j + lr) * 72 + 16 * i + 4 * g] = pk;
    }
  }

  f32x4 o[2][4] = {};
#pragma unroll
  for (int ks = 0; ks < 2; ++ks) {
    bf16x8 a2[2], b2[4];
#pragma unroll
    for (int i2 = 0; i2 < 2; ++i2)
      a2[i2] = *(const bf16x8*)&vt[(16 * i2 + lr) * 72 + 32 * ks + 8 * g];
#pragma unroll
    for (int j2 = 0; j2 < 4; ++j2)
      b2[j2] = *(const bf16x8*)&p_lds[(16 * j2 + lr) * 72 + 32 * ks + 8 * g];
#pragma unroll
    for (int i2 = 0; i2 < 2; ++i2)
#pragma unroll
      for (int j2 = 0; j2 < 4; ++j2)
        o[i2][j2] = __builtin_amdgcn_mfma_f32_16x16x32_bf16(a2[i2], b2[j2], o[i2][j2], 0, 0, 0);
  }

#pragma unroll
  for (int j2 = 0; j2 < 4; ++j2) {
    const int q = 16 * j2 + lr;
    if (q <= 48) {
#pragma unroll
      for (int i2 = 0; i2 < 2; ++i2) {
        ushort4 ok;
        ok.x = f2bfu(o[i2][j2][0]);
        ok.y = f2bfu(o[i2][j2][1]);
        ok.z = f2bfu(o[i2][j2][2]);
        ok.w = f2bfu(o[i2][j2][3]);
        *(ushort4*)&attnO[(rowbase + q) * DMODEL + h * 32 + 16 * i2 + 4 * g] = ok;
      }
    }
  }
}

extern "C" void kernel_launch(void* const* d_in, const int* in_sizes, int n_in,
                              void* d_out, int out_size, void* d_ws, size_t ws_size,
                              hipStream_t stream) {
  const float* x     = (const float*)d_in[0];
  const float* Wqkv  = (const float*)d_in[1];
  const float* bqkv  = (const float*)d_in[2];
  const float* Wproj = (const float*)d_in[3];
  const float* bproj = (const float*)d_in[4];
  float* out = (float*)d_out;

  char* ws = (char*)d_ws;
  __bf16* Xw     = (__bf16*)ws;  ws += (size_t)TOK * DMODEL * 2;   // 38.5 MB
  __bf16* qkvb   = (__bf16*)ws;  ws += (size_t)TOK * NQKV * 2;     // 115.6 MB
  __bf16* attnO  = (__bf16*)ws;  ws += (size_t)TOK * DMODEL * 2;   // 38.5 MB
  __bf16* attnP  = (__bf16*)ws;  ws += (size_t)TOK * DMODEL * 2;   // 38.5 MB
  __bf16* WqkvT  = (__bf16*)ws;  ws += (size_t)NQKV * DMODEL * 2;
  __bf16* WprojT = (__bf16*)ws;

  gather_x<<<dim3(8, 8, 16), 256, 0, stream>>>(x, Xw);
  conv_w<<<1728, 256, 0, stream>>>(Wqkv, Wproj, WqkvT, WprojT);
  gemm256<<<dim3(NQKV / 128, TOK / 256), 256, 0, stream>>>(Xw, WqkvT, bqkv, qkvb, NQKV);
  attn_mfma<<<dim3(NWIN, 12), 64, 0, stream>>>(qkvb, attnO);
  gemm256<<<dim3(DMODEL / 128, TOK / 256), 256, 0, stream>>>(attnO, WprojT, bproj, attnP, DMODEL);
  unscatter<<<dim3(8, 8, 16), 256, 0, stream>>>(attnP, out);
}